// Round 5
// baseline (401.588 us; speedup 1.0000x reference)
//
#include <hip/hip_runtime.h>
#include <hip/hip_bf16.h>

// ---------------------------------------------------------------------------
// myGRUCell low-rank fused monolith, R5: wave-private strips, register-resident
// MFMA A-operands, 2 barriers total, raw v_exp/v_rcp transcendentals.
//
//   512 threads (8 waves), 64 rows/block, grid 512.
//   wave w: strip g=w&3 (rows 16g..16g+15), col-half = w>>2 (cols half*512..).
//   Phase 0: wave (g,m) computes xW (m=0) or hU (m=1) for strip g -> sS[g].
//   barrier 1.  A-frags xW|hU -> registers (16 VGPR).
//   Phase 1: per wave, 8 tiles of 64 cols: pre_r GEMM -> sigmoid -> rh ->
//            per-wave LDS transpose (lgkmcnt only) -> rhU partial accumulate.
//   barrier 2 (pair-reduce rhU partials, f32).  rhU A-frags -> registers.
//   Phase 2: per wave, 8 tiles of 64 cols: r/z/c GEMMs (A from regs), gate,
//            store.  No barriers, no LDS.
// ws: bf16 weights:
//   [0      ..65535 ] Wt  [64][1024]
//   [65536  ..131071] Ut  [64][1024]
//   [131072 ..262143] P1t [1024][128] (k<64: W1, else U1)
//   [262144 ..393215] P2t [1024][128]
//   [393216 ..524287] P3t [1024][128] (k<64: W3, else U3)
// ---------------------------------------------------------------------------

typedef __attribute__((ext_vector_type(8))) short short8;   // 8 x bf16
typedef __attribute__((ext_vector_type(4))) float f32x4;
typedef __attribute__((ext_vector_type(4))) float f4;

#define WS_UT   65536
#define WS_P1T  131072
#define WS_P2T  262144
#define WS_P3T  393216

__device__ __forceinline__ short f2bf(float f) {
  unsigned u = __builtin_bit_cast(unsigned, f);
  u += 0x7FFFu + ((u >> 16) & 1u);          // round-nearest-even
  return (short)(u >> 16);
}

__device__ __forceinline__ short8 cvt8(f4 a, f4 b) {
  short8 r;
#pragma unroll
  for (int j = 0; j < 4; ++j) { r[j] = f2bf(a[j]); r[4 + j] = f2bf(b[j]); }
  return r;
}

__device__ __forceinline__ f32x4 mfma16(short8 a, short8 b, f32x4 c) {
  return __builtin_amdgcn_mfma_f32_16x16x32_bf16(a, b, c, 0, 0, 0);
}

// bf16 LDS tile, 128-col rows, XOR swizzle on 16B granules (bits 3..5 of col).
__device__ __forceinline__ short8 rdS(const short* b, int row, int col) {
  return *reinterpret_cast<const short8*>(b + row * 128 + (col ^ ((row & 7) << 3)));
}
__device__ __forceinline__ void wrS(short* b, int row, int col, short v) {
  b[row * 128 + (col ^ ((row & 7) << 3))] = v;
}

// fast transcendentals: v_exp_f32 (2^x) + v_rcp_f32, no libm
#define LOG2E 1.4426950408889634f
__device__ __forceinline__ float sigm_f(float v) {
  return __builtin_amdgcn_rcpf(1.f + __builtin_amdgcn_exp2f(-v * LOG2E));
}
__device__ __forceinline__ float tanh_f(float v) {
  float t = __builtin_amdgcn_exp2f(v * (2.f * LOG2E));       // e^{2v}
  return 1.f - 2.f * __builtin_amdgcn_rcpf(t + 1.f);
}

// ---------------------------------------------------------------------------
__global__ void prep_kernel(const float* __restrict__ W,  const float* __restrict__ W1,
                            const float* __restrict__ W2, const float* __restrict__ W3,
                            const float* __restrict__ U,  const float* __restrict__ U1,
                            const float* __restrict__ U2, const float* __restrict__ U3,
                            short* __restrict__ ws) {
  int i = blockIdx.x * blockDim.x + threadIdx.x;  // 0 .. 524287
  float v;
  if (i < 65536) {
    int n = i >> 10, k = i & 1023;
    v = W[k * 64 + n];
  } else if (i < 131072) {
    int j = i - 65536;
    int n = j >> 10, k = j & 1023;
    v = U[k * 64 + n];
  } else {
    int j = i - 131072;
    int sel = j >> 17;          // 0,1,2
    int jj = j & 131071;
    int n = jj >> 7, k = jj & 127;
    const float* Wk = sel == 0 ? W1 : sel == 1 ? W2 : W3;
    const float* Uk = sel == 0 ? U1 : sel == 1 ? U2 : U3;
    v = (k < 64) ? Wk[k * 1024 + n] : Uk[(k - 64) * 1024 + n];
  }
  ws[i] = f2bf(v);
}

// ---------------------------------------------------------------------------
__global__ __launch_bounds__(512, 4) void gru_fused(
    const float* __restrict__ x, const float* __restrict__ h,
    const float* __restrict__ u1d, const float* __restrict__ u2d,
    const float* __restrict__ u3d,
    const float* __restrict__ biasR, const float* __restrict__ biasZ,
    const float* __restrict__ biasU,
    const short* __restrict__ ws, float* __restrict__ out) {
  const short* Wt  = ws;
  const short* Ut  = ws + WS_UT;
  const short* P1t = ws + WS_P1T;
  const short* P2t = ws + WS_P2T;
  const short* P3t = ws + WS_P3T;

  __shared__ __align__(16) short sS[4][16 * 128];   // xW|hU per strip (bf16)
  __shared__ __align__(16) short sT[8][16 * 128];   // per-wave scratch

  const int tid  = threadIdx.x;
  const int w    = tid >> 6;      // wave 0..7
  const int l    = tid & 63;
  const int l15  = l & 15;
  const int lg   = l >> 4;
  const int g    = w & 3;         // 16-row strip
  const int half = w >> 2;        // col half (and phase-0 matrix select)
  const int r0   = blockIdx.x * 64;
  const int sr   = r0 + 16 * g;   // strip global row base

  short* sSg = &sS[g][0];
  short* sTw = &sT[w][0];

  // ---- Phase 0: strip g, matrix half (0: xW, 1: hU).  Depth-2 prefetch.
  {
    const float* srow = (half ? h : x) + (size_t)(sr + l15) * 1024 + lg * 8;
    const short* Bt0  = (half ? Ut : Wt) + (size_t)l15 * 1024 + lg * 8;
    f32x4 acc[4] = {};

    f4 xa = *reinterpret_cast<const f4*>(srow);
    f4 xb = *reinterpret_cast<const f4*>(srow + 4);
    short8 bw[4];
#pragma unroll
    for (int cf = 0; cf < 4; ++cf)
      bw[cf] = *reinterpret_cast<const short8*>(Bt0 + cf * 16 * 1024);

    for (int k0 = 0; k0 < 1024; k0 += 32) {
      f4 na = xa, nb = xb;
      short8 nw[4] = {bw[0], bw[1], bw[2], bw[3]};
      if (k0 + 32 < 1024) {
        na = *reinterpret_cast<const f4*>(srow + k0 + 32);
        nb = *reinterpret_cast<const f4*>(srow + k0 + 36);
#pragma unroll
        for (int cf = 0; cf < 4; ++cf)
          nw[cf] = *reinterpret_cast<const short8*>(Bt0 + cf * 16 * 1024 + k0 + 32);
      }
      short8 av = cvt8(xa, xb);
#pragma unroll
      for (int cf = 0; cf < 4; ++cf) acc[cf] = mfma16(av, bw[cf], acc[cf]);
      xa = na; xb = nb;
#pragma unroll
      for (int cf = 0; cf < 4; ++cf) bw[cf] = nw[cf];
    }
#pragma unroll
    for (int cf = 0; cf < 4; ++cf)
#pragma unroll
      for (int j = 0; j < 4; ++j)
        wrS(sSg, lg * 4 + j, half * 64 + cf * 16 + l15, f2bf(acc[cf][j]));
  }
  __syncthreads();   // barrier 1: xW|hU strips complete

  // xW|hU A-frags -> registers (K = 0..127)
  short8 axh[4];
#pragma unroll
  for (int k0 = 0; k0 < 4; ++k0)
    axh[k0] = rdS(sSg, l15, k0 * 32 + lg * 8);

  const int cb = half * 512;      // this wave's column base

  // ---- Phase 1: 8 tiles of 64 cols; rhU partial accumulation. No barriers.
  f32x4 accU[4] = {};
#pragma unroll 1
  for (int t = 0; t < 8; ++t) {
    const int n0 = cb + t * 64;

    // hoisted h gather (consumed after the GEMM below)
    float hv[4][4];
#pragma unroll
    for (int cf = 0; cf < 4; ++cf)
#pragma unroll
      for (int j = 0; j < 4; ++j)
        hv[cf][j] = h[(size_t)(sr + lg * 4 + j) * 1024 + n0 + cf * 16 + l15];

    // pre_r GEMM (A from registers)
    f32x4 accR[4] = {};
#pragma unroll
    for (int k0 = 0; k0 < 4; ++k0)
#pragma unroll
      for (int cf = 0; cf < 4; ++cf) {
        short8 b = *reinterpret_cast<const short8*>(
            P1t + (size_t)(n0 + cf * 16 + l15) * 128 + k0 * 32 + lg * 8);
        accR[cf] = mfma16(axh[k0], b, accR[cf]);
      }

    // sigmoid -> rh -> per-wave transpose scratch (cols 0..63 of sTw)
#pragma unroll
    for (int cf = 0; cf < 4; ++cf) {
      const int cc = n0 + cf * 16 + l15;
      float d1 = u1d[cc], b_r = biasR[cc];
#pragma unroll
      for (int j = 0; j < 4; ++j) {
        float rv = sigm_f(accR[cf][j] + hv[cf][j] * d1 + b_r);
        wrS(sTw, lg * 4 + j, cf * 16 + l15, f2bf(rv * hv[cf][j]));
      }
    }
    // wave-coherent LDS: compiler inserts lgkmcnt wait; no block barrier.
    short8 arh[2];
#pragma unroll
    for (int kk = 0; kk < 2; ++kk)
      arh[kk] = rdS(sTw, l15, kk * 32 + lg * 8);

    // rhU partial += rh_tile @ U[n0..n0+63, :]
#pragma unroll
    for (int kk = 0; kk < 2; ++kk)
#pragma unroll
      for (int cf = 0; cf < 4; ++cf) {
        short8 b = *reinterpret_cast<const short8*>(
            Ut + (size_t)(cf * 16 + l15) * 1024 + n0 + kk * 32 + lg * 8);
        accU[cf] = mfma16(arh[kk], b, accU[cf]);
      }
  }

  // write f32 rhU partial to own scratch ([16][64] f32, 4-float-granule swizzle)
  {
    float* fT = reinterpret_cast<float*>(sTw);
#pragma unroll
    for (int cf = 0; cf < 4; ++cf)
#pragma unroll
      for (int j = 0; j < 4; ++j) {
        int row = lg * 4 + j, col = cf * 16 + l15;
        fT[row * 64 + (col ^ ((row & 7) << 2))] = accU[cf][j];
      }
  }
  __syncthreads();   // barrier 2: partials complete

  // pair-reduce partials (w and w^4 share strip g), build rhU A-frags
  short8 arhu[2];
  {
    const float* fA = reinterpret_cast<const float*>(sTw);
    const float* fB = reinterpret_cast<const float*>(&sT[w ^ 4][0]);
    const int sw = (l15 & 7) << 2;
#pragma unroll
    for (int kk = 0; kk < 2; ++kk) {
      const int c0 = kk * 32 + lg * 8;
      f4 pa = *reinterpret_cast<const f4*>(fA + l15 * 64 + (c0 ^ sw));
      f4 pb = *reinterpret_cast<const f4*>(fA + l15 * 64 + ((c0 + 4) ^ sw));
      f4 qa = *reinterpret_cast<const f4*>(fB + l15 * 64 + (c0 ^ sw));
      f4 qb = *reinterpret_cast<const f4*>(fB + l15 * 64 + ((c0 + 4) ^ sw));
      arhu[kk] = cvt8(pa + qa, pb + qb);
    }
  }

  // ---- Phase 2: 8 tiles of 64 cols; r/z/c GEMMs from registers; store.
#pragma unroll 1
  for (int t = 0; t < 8; ++t) {
    const int n0 = cb + t * 64;

    float hv[4][4];
#pragma unroll
    for (int cf = 0; cf < 4; ++cf)
#pragma unroll
      for (int j = 0; j < 4; ++j)
        hv[cf][j] = h[(size_t)(sr + lg * 4 + j) * 1024 + n0 + cf * 16 + l15];

    f32x4 aR[4] = {}, aZ[4] = {}, aC[4] = {};
#pragma unroll
    for (int k0 = 0; k0 < 4; ++k0) {
      short8 a3 = (k0 < 2) ? axh[k0] : arhu[k0 - 2];
#pragma unroll
      for (int cf = 0; cf < 4; ++cf) {
        const size_t bo = (size_t)(n0 + cf * 16 + l15) * 128 + k0 * 32 + lg * 8;
        short8 b1 = *reinterpret_cast<const short8*>(P1t + bo);
        short8 b2 = *reinterpret_cast<const short8*>(P2t + bo);
        short8 b3 = *reinterpret_cast<const short8*>(P3t + bo);
        aR[cf] = mfma16(axh[k0], b1, aR[cf]);
        aZ[cf] = mfma16(axh[k0], b2, aZ[cf]);
        aC[cf] = mfma16(a3,      b3, aC[cf]);
      }
    }

#pragma unroll
    for (int cf = 0; cf < 4; ++cf) {
      const int cc = n0 + cf * 16 + l15;
      float d1 = u1d[cc], d2 = u2d[cc], d3 = u3d[cc];
      float b_r = biasR[cc], b_z = biasZ[cc], b_u = biasU[cc];
#pragma unroll
      for (int j = 0; j < 4; ++j) {
        size_t gi = (size_t)(sr + lg * 4 + j) * 1024 + cc;
        float hvj = hv[cf][j];
        float rv = sigm_f(aR[cf][j] + hvj * d1 + b_r);
        float zv = sigm_f(aZ[cf][j] + hvj * d2 + b_z);
        float cv = tanh_f(aC[cf][j] + rv * hvj * d3 + b_u);
        out[gi] = zv * hvj + (1.f - zv) * cv;
      }
    }
  }
}

extern "C" void kernel_launch(void* const* d_in, const int* in_sizes, int n_in,
                              void* d_out, int out_size, void* d_ws, size_t ws_size,
                              hipStream_t stream) {
  const float* x   = (const float*)d_in[0];
  const float* h   = (const float*)d_in[1];
  const float* W   = (const float*)d_in[2];
  const float* W1  = (const float*)d_in[3];
  const float* W2  = (const float*)d_in[4];
  const float* W3  = (const float*)d_in[5];
  const float* U   = (const float*)d_in[6];
  const float* U1  = (const float*)d_in[7];
  const float* U2  = (const float*)d_in[8];
  const float* U3  = (const float*)d_in[9];
  const float* u1d = (const float*)d_in[10];
  const float* u2d = (const float*)d_in[11];
  const float* u3d = (const float*)d_in[12];
  const float* bR  = (const float*)d_in[13];
  const float* bZ  = (const float*)d_in[14];
  const float* bU  = (const float*)d_in[15];
  short* ws = (short*)d_ws;

  prep_kernel<<<2048, 256, 0, stream>>>(W, W1, W2, W3, U, U1, U2, U3, ws);
  gru_fused<<<512, 512, 0, stream>>>(x, h, u1d, u2d, u3d, bR, bZ, bU, ws, (float*)d_out);
}